// Round 5
// baseline (432.682 us; speedup 1.0000x reference)
//
#include <hip/hip_runtime.h>

#define N_NODES 50000
#define N_EDGES 800000
#define D 64          // NODE_DIM == MSG_DIM
#define EDIM 4
#define IN_DIM 132    // 2*D + EDIM
#define H3 192        // 3*D

// ---------------- CSR build ----------------

__global__ void k_count(const int* __restrict__ dst, int* __restrict__ deg) {
    int e = blockIdx.x * blockDim.x + threadIdx.x;
    if (e < N_EDGES) atomicAdd(&deg[dst[e]], 1);
}

__global__ __launch_bounds__(256) void k_scan1(const int* __restrict__ deg,
                                               int* __restrict__ offsets,
                                               int* __restrict__ bsum) {
    __shared__ int sm[256];
    int tid = threadIdx.x;
    int i = blockIdx.x * 256 + tid;
    int x = (i < N_NODES) ? deg[i] : 0;
    sm[tid] = x;
    __syncthreads();
    for (int s = 1; s < 256; s <<= 1) {
        int v = (tid >= s) ? sm[tid - s] : 0;
        __syncthreads();
        sm[tid] += v;
        __syncthreads();
    }
    if (i < N_NODES) offsets[i] = sm[tid] - x;  // block-local exclusive
    if (tid == 255) bsum[blockIdx.x] = sm[255];
}

__global__ __launch_bounds__(256) void k_scan2(const int* __restrict__ bsum,
                                               int* __restrict__ boff, int nblk) {
    __shared__ int sm[256];
    int tid = threadIdx.x;
    int x = (tid < nblk) ? bsum[tid] : 0;
    sm[tid] = x;
    __syncthreads();
    for (int s = 1; s < 256; s <<= 1) {
        int v = (tid >= s) ? sm[tid - s] : 0;
        __syncthreads();
        sm[tid] += v;
        __syncthreads();
    }
    if (tid < nblk) boff[tid] = sm[tid] - x;  // exclusive
}

__global__ __launch_bounds__(256) void k_scan3(int* __restrict__ offsets,
                                               const int* __restrict__ boff) {
    int i = blockIdx.x * 256 + threadIdx.x;
    if (i < N_NODES) offsets[i] += boff[blockIdx.x];
}

__global__ void k_fill(const int* __restrict__ src, const int* __restrict__ dst,
                       const int* __restrict__ offsets, int* __restrict__ cursor,
                       int* __restrict__ csr_src, int* __restrict__ csr_eid) {
    int e = blockIdx.x * blockDim.x + threadIdx.x;
    if (e < N_EDGES) {
        int d = dst[e];
        int pos = offsets[d] + atomicAdd(&cursor[d], 1);
        csr_src[pos] = src[e];
        csr_eid[pos] = e;
    }
}

// ---------------- reduce: S[n] = sum_{e->n} hv[src_e]; (round0) Hsum[n] = sum he_e --------

template <int ROUND>
__global__ __launch_bounds__(256) void k_reduce(const float* __restrict__ hv,
                                                const float* __restrict__ he,
                                                const int* __restrict__ csr_src,
                                                const int* __restrict__ csr_eid,
                                                const int* __restrict__ offsets,
                                                const int* __restrict__ deg,
                                                float* __restrict__ S,
                                                float* __restrict__ Hsum) {
    int wave = (blockIdx.x * blockDim.x + threadIdx.x) >> 6;
    if (wave >= N_NODES) return;
    int lane = threadIdx.x & 63;
    int g = lane >> 4;   // edge slot 0..3
    int c = lane & 15;   // float4 chunk of the row
    const int off = offsets[wave];
    const int cnt = deg[wave];
    float4 acc = make_float4(0.f, 0.f, 0.f, 0.f);
    float4 hacc = make_float4(0.f, 0.f, 0.f, 0.f);
    for (int e = g; e < cnt; e += 4) {
        int sn = csr_src[off + e];
        float4 v = ((const float4*)(hv + (size_t)sn * D))[c];
        acc.x += v.x; acc.y += v.y; acc.z += v.z; acc.w += v.w;
        if (ROUND == 0 && c == 0) {
            int eid = csr_eid[off + e];
            float4 h = *(const float4*)(he + (size_t)eid * EDIM);
            hacc.x += h.x; hacc.y += h.y; hacc.z += h.z; hacc.w += h.w;
        }
    }
    acc.x += __shfl_xor(acc.x, 16); acc.y += __shfl_xor(acc.y, 16);
    acc.z += __shfl_xor(acc.z, 16); acc.w += __shfl_xor(acc.w, 16);
    acc.x += __shfl_xor(acc.x, 32); acc.y += __shfl_xor(acc.y, 32);
    acc.z += __shfl_xor(acc.z, 32); acc.w += __shfl_xor(acc.w, 32);
    if (ROUND == 0) {
        hacc.x += __shfl_xor(hacc.x, 16); hacc.y += __shfl_xor(hacc.y, 16);
        hacc.z += __shfl_xor(hacc.z, 16); hacc.w += __shfl_xor(hacc.w, 16);
        hacc.x += __shfl_xor(hacc.x, 32); hacc.y += __shfl_xor(hacc.y, 32);
        hacc.z += __shfl_xor(hacc.z, 32); hacc.w += __shfl_xor(hacc.w, 32);
    }
    if (g == 0) ((float4*)(S + (size_t)wave * D))[c] = acc;
    if (ROUND == 0 && lane == 0) *(float4*)(Hsum + (size_t)wave * EDIM) = hacc;
}

// ---------------- node update: lane = node, wave = j-tile, weights via SGPR ----------------
// 512 threads = 8 waves; 64 nodes per block (lane = local node).
// XT[k][n] k-major stride 64 (bank = n mod 32: broadcast/2-way reads, conflict-free-ish).
//   rows 0..63: S^T (GEMM1) then a^T (GEMM2); rows 64..127: hv^T; 128..131: Hsum^T.
// Wave w owns j-tile jb = w*8. GEMM1: 8 cols of Wm. GEMM2: cols {jb,jb+64,jb+128} of Wi/Wh.
// Weight addresses are wave-uniform (readfirstlane) -> s_load through scalar cache,
// leaving vector L1 idle (R2's bottleneck).

__global__ __launch_bounds__(512) void k_node(const float* __restrict__ hv_in,
                                              const float* __restrict__ S,
                                              const float* __restrict__ Hsum,
                                              const int* __restrict__ deg,
                                              const float* __restrict__ W_msg,
                                              const float* __restrict__ b_msg,
                                              const float* __restrict__ W_ih,
                                              const float* __restrict__ W_hh,
                                              const float* __restrict__ b_ih,
                                              const float* __restrict__ b_hh,
                                              float* __restrict__ hv_out, int t) {
    __shared__ float XT[IN_DIM * D];  // 33792 B

    const int tid = threadIdx.x;
    const int n_base = blockIdx.x * D;

    // ---- stage S^T, hv^T, Hsum^T ----
    {
        int nl = tid >> 3;  // 0..63
        int c = tid & 7;    // 0..7 (8-float chunk)
        int n = n_base + nl;
        if (n >= N_NODES) n = N_NODES - 1;
        const float4* Sp = (const float4*)(S + (size_t)n * D);
        const float4* Hp = (const float4*)(hv_in + (size_t)n * D);
        float4 s0 = Sp[c * 2], s1 = Sp[c * 2 + 1];
        float4 h0 = Hp[c * 2], h1 = Hp[c * 2 + 1];
        int k0 = c * 8;
        XT[(k0 + 0) * D + nl] = s0.x; XT[(k0 + 1) * D + nl] = s0.y;
        XT[(k0 + 2) * D + nl] = s0.z; XT[(k0 + 3) * D + nl] = s0.w;
        XT[(k0 + 4) * D + nl] = s1.x; XT[(k0 + 5) * D + nl] = s1.y;
        XT[(k0 + 6) * D + nl] = s1.z; XT[(k0 + 7) * D + nl] = s1.w;
        XT[(64 + k0 + 0) * D + nl] = h0.x; XT[(64 + k0 + 1) * D + nl] = h0.y;
        XT[(64 + k0 + 2) * D + nl] = h0.z; XT[(64 + k0 + 3) * D + nl] = h0.w;
        XT[(64 + k0 + 4) * D + nl] = h1.x; XT[(64 + k0 + 5) * D + nl] = h1.y;
        XT[(64 + k0 + 6) * D + nl] = h1.z; XT[(64 + k0 + 7) * D + nl] = h1.w;
        if (c == 0) {
            float4 hs = *(const float4*)(Hsum + (size_t)n * EDIM);
            XT[128 * D + nl] = hs.x; XT[129 * D + nl] = hs.y;
            XT[130 * D + nl] = hs.z; XT[131 * D + nl] = hs.w;
        }
    }
    __syncthreads();

    const int lane = tid & 63;
    const int w = __builtin_amdgcn_readfirstlane(tid) >> 6;  // wave id 0..7 (uniform)
    const int jb = w * 8;
    const int n = n_base + lane;
    const bool nvalid = (n < N_NODES);
    const int nc = nvalid ? n : N_NODES - 1;
    const float degf = (float)deg[nc];

    const float* __restrict__ Wm = W_msg + (size_t)t * IN_DIM * D;

    // ---- GEMM1: acc1 = S@Wa (+Hsum@Wc), acc2 = hv@Wb ----
    float acc1[8], acc2[8];
#pragma unroll
    for (int i = 0; i < 8; ++i) { acc1[i] = 0.f; acc2[i] = 0.f; }

#pragma unroll 4
    for (int k = 0; k < 64; ++k) {
        float aS = XT[k * D + lane];
        float aH = XT[(64 + k) * D + lane];
        const float* wr1 = Wm + k * D + jb;
        const float* wr2 = Wm + (64 + k) * D + jb;
#pragma unroll
        for (int i = 0; i < 8; ++i) {
            acc1[i] = fmaf(aS, wr1[i], acc1[i]);
            acc2[i] = fmaf(aH, wr2[i], acc2[i]);
        }
    }
#pragma unroll
    for (int q = 0; q < 4; ++q) {
        float aQ = XT[(128 + q) * D + lane];
        const float* wr = Wm + (128 + q) * D + jb;
#pragma unroll
        for (int i = 0; i < 8; ++i) acc1[i] = fmaf(aQ, wr[i], acc1[i]);
    }

    const float* bmp = b_msg + (size_t)t * D + jb;
    float av[8];
#pragma unroll
    for (int i = 0; i < 8; ++i) av[i] = acc1[i] + degf * (acc2[i] + bmp[i]);

    __syncthreads();  // all waves done reading S rows
#pragma unroll
    for (int i = 0; i < 8; ++i) XT[(jb + i) * D + lane] = av[i];  // a^T into rows 0..63
    __syncthreads();

    // ---- GEMM2 ----
    const float* __restrict__ Wi = W_ih + (size_t)t * D * H3;
    const float* __restrict__ Wh = W_hh + (size_t)t * D * H3;
    const float* bi = b_ih + (size_t)t * H3;
    const float* bh = b_hh + (size_t)t * H3;

    float aR[8], aZ[8], aN[8], aHN[8];
#pragma unroll
    for (int i = 0; i < 8; ++i) {
        aR[i] = bi[jb + i] + bh[jb + i];
        aZ[i] = bi[64 + jb + i] + bh[64 + jb + i];
        aN[i] = bi[128 + jb + i];
        aHN[i] = bh[128 + jb + i];
    }

#pragma unroll 4
    for (int k = 0; k < 64; ++k) {  // A = a^T rows, B = Wi
        float Aa = XT[k * D + lane];
        const float* wr = Wi + k * H3;
#pragma unroll
        for (int i = 0; i < 8; ++i) {
            aR[i] = fmaf(Aa, wr[jb + i], aR[i]);
            aZ[i] = fmaf(Aa, wr[64 + jb + i], aZ[i]);
            aN[i] = fmaf(Aa, wr[128 + jb + i], aN[i]);
        }
    }
#pragma unroll 4
    for (int k = 0; k < 64; ++k) {  // A = hv^T rows, B = Wh
        float Ah = XT[(64 + k) * D + lane];
        const float* wr = Wh + k * H3;
#pragma unroll
        for (int i = 0; i < 8; ++i) {
            aR[i] = fmaf(Ah, wr[jb + i], aR[i]);
            aZ[i] = fmaf(Ah, wr[64 + jb + i], aZ[i]);
            aHN[i] = fmaf(Ah, wr[128 + jb + i], aHN[i]);
        }
    }

    // ---- GRU combine + store ----
    float o[8];
#pragma unroll
    for (int i = 0; i < 8; ++i) {
        float r = 1.f / (1.f + __expf(-aR[i]));
        float z = 1.f / (1.f + __expf(-aZ[i]));
        float nin = aN[i] + r * aHN[i];
        float nn = 2.f / (1.f + __expf(-2.f * nin)) - 1.f;
        float hold = XT[(64 + jb + i) * D + lane];
        o[i] = (1.f - z) * nn + z * hold;
    }
    if (nvalid) {
        float4* op = (float4*)(hv_out + (size_t)n * D + jb);
        op[0] = make_float4(o[0], o[1], o[2], o[3]);
        op[1] = make_float4(o[4], o[5], o[6], o[7]);
    }
}

// ---------------- launch ----------------

extern "C" void kernel_launch(void* const* d_in, const int* in_sizes, int n_in,
                              void* d_out, int out_size, void* d_ws, size_t ws_size,
                              hipStream_t stream) {
    const float* hv = (const float*)d_in[0];
    const float* he = (const float*)d_in[1];
    const float* W_msg = (const float*)d_in[2];
    const float* b_msg = (const float*)d_in[3];
    const float* W_ih = (const float*)d_in[4];
    const float* W_hh = (const float*)d_in[5];
    const float* b_ih = (const float*)d_in[6];
    const float* b_hh = (const float*)d_in[7];
    const int* src = (const int*)d_in[8];
    const int* dst = (const int*)d_in[9];
    float* out = (float*)d_out;

    char* p = (char*)d_ws;
    int* deg = (int*)p;        p += (size_t)N_NODES * sizeof(int);
    int* cursor = (int*)p;     p += (size_t)N_NODES * sizeof(int);
    int* offsets = (int*)p;    p += (size_t)N_NODES * sizeof(int);
    int* bsum = (int*)p;       p += 256 * sizeof(int);
    int* boff = (int*)p;       p += 256 * sizeof(int);
    int* csr_src = (int*)p;    p += (size_t)N_EDGES * sizeof(int);
    float* Hsum = (float*)p;   p += (size_t)N_NODES * EDIM * sizeof(float);
    float* S = (float*)p;      p += (size_t)N_NODES * D * sizeof(float);
    float* hv_buf = (float*)p; p += (size_t)N_NODES * D * sizeof(float);
    // csr_eid aliases hv_buf: consumed by k_reduce<0> before k_node writes hv_buf
    int* csr_eid = (int*)hv_buf;

    const int NBLK = (N_NODES + 255) / 256;  // 196

    hipMemsetAsync(deg, 0, N_NODES * sizeof(int), stream);
    hipMemsetAsync(cursor, 0, N_NODES * sizeof(int), stream);

    k_count<<<(N_EDGES + 255) / 256, 256, 0, stream>>>(dst, deg);
    k_scan1<<<NBLK, 256, 0, stream>>>(deg, offsets, bsum);
    k_scan2<<<1, 256, 0, stream>>>(bsum, boff, NBLK);
    k_scan3<<<NBLK, 256, 0, stream>>>(offsets, boff);
    k_fill<<<(N_EDGES + 255) / 256, 256, 0, stream>>>(src, dst, offsets, cursor, csr_src, csr_eid);

    const int RBLK = (N_NODES * 64 + 255) / 256;  // wave per node
    const int GBLK = (N_NODES + 63) / 64;         // 64 nodes per block, 512 threads

    // round 0: read input hv, write hv_buf
    k_reduce<0><<<RBLK, 256, 0, stream>>>(hv, he, csr_src, csr_eid, offsets, deg, S, Hsum);
    k_node<<<GBLK, 512, 0, stream>>>(hv, S, Hsum, deg, W_msg, b_msg, W_ih, W_hh, b_ih, b_hh, hv_buf, 0);

    // round 1: read hv_buf, write d_out
    k_reduce<1><<<RBLK, 256, 0, stream>>>(hv_buf, he, csr_src, csr_eid, offsets, deg, S, Hsum);
    k_node<<<GBLK, 512, 0, stream>>>(hv_buf, S, Hsum, deg, W_msg, b_msg, W_ih, W_hh, b_ih, b_hh, out, 1);
}